// Round 4
// baseline (565.793 us; speedup 1.0000x reference)
//
#include <hip/hip_runtime.h>

typedef unsigned short ushort_t;
typedef __attribute__((ext_vector_type(8))) short short8;
typedef __attribute__((ext_vector_type(4))) float f32x4;

template <typename T> struct is_fp32 { static constexpr bool value = false; };
template <> struct is_fp32<float> { static constexpr bool value = true; };

#define B_ 2
#define HW_ 65536          // 256*256 per batch
#define MTOT_ 131072       // B*H*W rows
#define C_ 192
#define C3_ 576
#define HEADS_ 4
#define CH_ 48

// ---- workspace layout (bytes), total ~302.5 MB ----
#define OFF_QKV0  ((size_t)0)                       // bf16 131072*576*2 = 150,994,944
#define OFF_QKV1  ((size_t)150994944)               // bf16, same size
#define OFF_BT    ((size_t)301989888)               // w_qkv^T bf16 576*192*2 = 221,184
#define OFF_S     ((size_t)302211072)               // fp32 8*48*48 = 73,728 B
#define OFF_NQ    ((size_t)302284800)               // fp32 8*48 = 1,536 B
#define OFF_NK    ((size_t)302286336)               // fp32 8*48 = 1,536 B
#define OFF_ATTN  ((size_t)302287872)               // fp32 8*48*48 = 73,728 B
#define OFF_WB    OFF_ATTN                          // bf16 dw weights 9*576*2 = 10,368 B;
                                                    // aliases ATT (dead until k4a, after dwconv)
#define OFF_MT    ((size_t)302361600)               // bf16 2*192*192 = 147,456 B

__device__ __forceinline__ float b2f(ushort_t u) {
    unsigned v = ((unsigned)u) << 16;
    return __builtin_bit_cast(float, v);
}
__device__ __forceinline__ ushort_t f2b(float f) {
    unsigned u = __builtin_bit_cast(unsigned, f);
    u = (u + 0x7fffu + ((u >> 16) & 1u)) >> 16;   // RNE
    return (ushort_t)u;
}
__device__ __forceinline__ void storev(float* p, float v) { *p = v; }
__device__ __forceinline__ void storev(ushort_t* p, float v) { *p = f2b(v); }

// K0a: transpose+convert w_qkv fp32 [192,576] -> bf16 [576,192]
__global__ void k0_transpose(const float* __restrict__ w, ushort_t* __restrict__ bt) {
    int idx = blockIdx.x * 256 + threadIdx.x;        // 576*192 = 110592 exactly
    int n = idx / 192, k = idx - n * 192;
    bt[idx] = f2b(w[k * 576 + n]);
}

// K0b: convert depthwise weights fp32 [9*576] -> bf16 (packed for uint4 loads)
__global__ void k0_cvt_w(const float* __restrict__ w, ushort_t* __restrict__ wb) {
    int idx = blockIdx.x * 256 + threadIdx.x;        // 5184 elems
    if (idx < 5184) wb[idx] = f2b(w[idx]);
}

// MFMA GEMM: C[M,N] = A[M,192] * BT[N,192]^T + bias(fp32).  64x64 tile, BK=64,
// 4 waves each 32x32 (2x2 of 16x16x32 bf16 mfma). A is fp32 (converted while
// staging) or bf16. bstride!=0 selects a per-batch B matrix by row/65536.
template <typename InT, typename OutT>
__global__ __launch_bounds__(256) void gemm_k192(
    const InT* __restrict__ A, int lda, int acol0,
    const ushort_t* __restrict__ BT, int bstride,
    const float* __restrict__ bias,
    OutT* __restrict__ Cout, int ldc)
{
    const int m0 = blockIdx.x * 64;
    const int n0 = blockIdx.y * 64;
    const ushort_t* bt = BT + (bstride ? (size_t)(m0 >> 16) * (size_t)bstride : 0);

    __shared__ ushort_t As[64 * 72];   // stride 72 elems: 16B-aligned rows
    __shared__ ushort_t Bs[64 * 72];

    const int t = threadIdx.x;
    const int wave = t >> 6, lane = t & 63;
    const int quad = lane >> 4, l15 = lane & 15;
    const int wm = (wave >> 1) * 32, wn = (wave & 1) * 32;
    const int srow = t >> 2, scol = (t & 3) * 16;

    f32x4 acc[2][2] = {};

    for (int kk = 0; kk < 192; kk += 64) {
        const InT* ga = A + (size_t)(m0 + srow) * lda + acol0 + kk + scol;
        if constexpr (is_fp32<InT>::value) {
            float4 f0 = *(const float4*)ga;
            float4 f1 = *(const float4*)(ga + 4);
            float4 f2 = *(const float4*)(ga + 8);
            float4 f3 = *(const float4*)(ga + 12);
            ushort_t o[16];
            o[0] = f2b(f0.x); o[1] = f2b(f0.y); o[2] = f2b(f0.z); o[3] = f2b(f0.w);
            o[4] = f2b(f1.x); o[5] = f2b(f1.y); o[6] = f2b(f1.z); o[7] = f2b(f1.w);
            o[8] = f2b(f2.x); o[9] = f2b(f2.y); o[10] = f2b(f2.z); o[11] = f2b(f2.w);
            o[12] = f2b(f3.x); o[13] = f2b(f3.y); o[14] = f2b(f3.z); o[15] = f2b(f3.w);
            *(uint4*)&As[srow * 72 + scol] = *(uint4*)&o[0];
            *(uint4*)&As[srow * 72 + scol + 8] = *(uint4*)&o[8];
        } else {
            uint4 va0 = *(const uint4*)ga;
            uint4 va1 = *(const uint4*)(ga + 8);
            *(uint4*)&As[srow * 72 + scol] = va0;
            *(uint4*)&As[srow * 72 + scol + 8] = va1;
        }
        const ushort_t* gb = bt + (size_t)(n0 + srow) * 192 + kk + scol;
        uint4 vb0 = *(const uint4*)gb;
        uint4 vb1 = *(const uint4*)(gb + 8);
        *(uint4*)&Bs[srow * 72 + scol] = vb0;
        *(uint4*)&Bs[srow * 72 + scol + 8] = vb1;
        __syncthreads();
#pragma unroll
        for (int ks = 0; ks < 2; ks++) {
            short8 a0 = *(const short8*)&As[(wm + l15) * 72 + ks * 32 + quad * 8];
            short8 a1 = *(const short8*)&As[(wm + 16 + l15) * 72 + ks * 32 + quad * 8];
            short8 b0 = *(const short8*)&Bs[(wn + l15) * 72 + ks * 32 + quad * 8];
            short8 b1 = *(const short8*)&Bs[(wn + 16 + l15) * 72 + ks * 32 + quad * 8];
            acc[0][0] = __builtin_amdgcn_mfma_f32_16x16x32_bf16(a0, b0, acc[0][0], 0, 0, 0);
            acc[0][1] = __builtin_amdgcn_mfma_f32_16x16x32_bf16(a0, b1, acc[0][1], 0, 0, 0);
            acc[1][0] = __builtin_amdgcn_mfma_f32_16x16x32_bf16(a1, b0, acc[1][0], 0, 0, 0);
            acc[1][1] = __builtin_amdgcn_mfma_f32_16x16x32_bf16(a1, b1, acc[1][1], 0, 0, 0);
        }
        __syncthreads();
    }
#pragma unroll
    for (int sm = 0; sm < 2; sm++) {
#pragma unroll
        for (int sn = 0; sn < 2; sn++) {
            int col = n0 + wn + sn * 16 + l15;
            float bv = bias ? bias[col] : 0.f;
#pragma unroll
            for (int r = 0; r < 4; r++) {
                int row = m0 + wm + sm * 16 + quad * 4 + r;
                storev(&Cout[(size_t)row * ldc + col], acc[sm][sn][r] + bv);
            }
        }
    }
}

// K2: 3x3 depthwise conv, SAME zero-pad. One thread = 8 channels x 4 vertical
// pixels: activation rows load once for up to 3 outputs, bf16 weights load once
// for all 4. Vmem per 16B output: 27 -> ~7.3 (kernel was TA-throughput bound).
__global__ void k2_dwconv(const ushort_t* __restrict__ qkv0, const ushort_t* __restrict__ wb,
                          const float* __restrict__ bdw, ushort_t* __restrict__ qkv1)
{
    int gid = blockIdx.x * 256 + threadIdx.x;      // 9216*256 = 2,359,296 = 32768*72
    int c8 = gid % 72;
    int g = gid / 72;                              // (batch, y-group, x)
    int x = g & 255, yg = (g >> 8) & 63, b = g >> 14;
    int y0 = yg * 4;
    int cbase = c8 * 8;

    // weights -> fp32 regs (9 taps x 8 ch)
    float wgt[9][8];
#pragma unroll
    for (int tap = 0; tap < 9; tap++) {
        uint4 wv = *(const uint4*)(wb + tap * C3_ + cbase);
        const ushort_t* ww = (const ushort_t*)&wv;
#pragma unroll
        for (int i = 0; i < 8; i++) wgt[tap][i] = b2f(ww[i]);
    }
    float4 bv0 = *(const float4*)(bdw + cbase);
    float4 bv1 = *(const float4*)(bdw + cbase + 4);
    float acc[4][8];
#pragma unroll
    for (int o = 0; o < 4; o++) {
        acc[o][0] = bv0.x; acc[o][1] = bv0.y; acc[o][2] = bv0.z; acc[o][3] = bv0.w;
        acc[o][4] = bv1.x; acc[o][5] = bv1.y; acc[o][6] = bv1.z; acc[o][7] = bv1.w;
    }

    const size_t pbase = (size_t)b * HW_ + (size_t)y0 * 256 + x;
#pragma unroll
    for (int d = -1; d <= 4; d++) {
        int yy = y0 + d;
        if (yy < 0 || yy > 255) continue;
#pragma unroll
        for (int kxi = 0; kxi < 3; kxi++) {
            int xx = x + kxi - 1;
            if (xx < 0 || xx > 255) continue;
            uint4 dv = *(const uint4*)(qkv0 + ((pbase + d * 256 + (kxi - 1)) * C3_ + cbase));
            const ushort_t* dd = (const ushort_t*)&dv;
            float v[8];
#pragma unroll
            for (int i = 0; i < 8; i++) v[i] = b2f(dd[i]);
#pragma unroll
            for (int o = 0; o < 4; o++) {
                if (d >= o - 1 && d <= o + 1) {
                    int ky = d - o + 1;              // 0..2
#pragma unroll
                    for (int i = 0; i < 8; i++) acc[o][i] += v[i] * wgt[ky * 3 + kxi][i];
                }
            }
        }
    }
#pragma unroll
    for (int o = 0; o < 4; o++) {
        ushort_t ov[8];
#pragma unroll
        for (int i = 0; i < 8; i++) ov[i] = f2b(acc[o][i]);
        *(uint4*)(qkv1 + (pbase + o * 256) * C3_ + cbase) = *(uint4*)ov;
    }
}

// K3: per (b,head) Gram matrix S[48,48] = sum_n q[n,cq]*k[n,ck], plus sum(q^2), sum(k^2)
// fused into the same LDS-staged pass. Partial sums -> global atomics.
__global__ __launch_bounds__(256) void k3_gram(const ushort_t* __restrict__ qkv1,
        float* __restrict__ S, float* __restrict__ NQ, float* __restrict__ NK)
{
    int bh = blockIdx.y;              // 0..7
    int b = bh >> 2, h = bh & 3;
    int n0 = blockIdx.x * 512;        // 128 slices of 512 rows
    __shared__ float Lq[32][49];
    __shared__ float Lk[32][49];
    int t = threadIdx.x;
    int cq0 = (t >> 4) * 3, ck0 = (t & 15) * 3;
    float acc[3][3] = {};
    float nacc = 0.f;

    for (int c0 = 0; c0 < 512; c0 += 32) {
        for (int i = t; i < 384; i += 256) {
            int row = i / 12, s = i - row * 12;
            int ch = (s < 6) ? (h * CH_ + s * 8) : (C_ + h * CH_ + (s - 6) * 8);
            uint4 d = *(const uint4*)(qkv1 + ((size_t)(b * HW_ + n0 + c0 + row)) * C3_ + ch);
            const ushort_t* dd = (const ushort_t*)&d;
            float* dst = (s < 6) ? &Lq[row][s * 8] : &Lk[row][(s - 6) * 8];
#pragma unroll
            for (int j = 0; j < 8; j++) dst[j] = b2f(dd[j]);
        }
        __syncthreads();
#pragma unroll 4
        for (int n = 0; n < 32; n++) {
            float q0 = Lq[n][cq0], q1 = Lq[n][cq0 + 1], q2 = Lq[n][cq0 + 2];
            float k0 = Lk[n][ck0], k1 = Lk[n][ck0 + 1], k2 = Lk[n][ck0 + 2];
            acc[0][0] += q0 * k0; acc[0][1] += q0 * k1; acc[0][2] += q0 * k2;
            acc[1][0] += q1 * k0; acc[1][1] += q1 * k1; acc[1][2] += q1 * k2;
            acc[2][0] += q2 * k0; acc[2][1] += q2 * k1; acc[2][2] += q2 * k2;
            if (t < 96) { float v = (t < 48) ? Lq[n][t] : Lk[n][t - 48]; nacc += v * v; }
        }
        __syncthreads();
    }
    float* Sp = S + bh * 2304;
#pragma unroll
    for (int i = 0; i < 3; i++)
#pragma unroll
        for (int j = 0; j < 3; j++)
            atomicAdd(&Sp[(cq0 + i) * 48 + ck0 + j], acc[i][j]);
    if (t < 48) atomicAdd(&NQ[bh * 48 + t], nacc);
    else if (t < 96) atomicAdd(&NK[bh * 48 + t - 48], nacc);
}

// K4a: attn = softmax_row( S * temp / (|q||k|) ), one 64-thread block per (bh,cq) row
__global__ void k4a_softmax(const float* __restrict__ S, const float* __restrict__ NQ,
                            const float* __restrict__ NK, const float* __restrict__ temp,
                            float* __restrict__ ATT)
{
    int bh = blockIdx.y, cq = blockIdx.x;
    int h = bh & 3;
    int t = threadIdx.x;
    float nq = fmaxf(sqrtf(NQ[bh * 48 + cq]), 1e-12f);
    float tv = temp[h];
    float logit = -1e30f;
    if (t < 48) {
        float nk = fmaxf(sqrtf(NK[bh * 48 + t]), 1e-12f);
        logit = S[bh * 2304 + cq * 48 + t] * tv / (nq * nk);
    }
    float m = logit;
    for (int o = 32; o > 0; o >>= 1) m = fmaxf(m, __shfl_xor(m, o));
    float e = (t < 48) ? __expf(logit - m) : 0.f;
    float ssum = e;
    for (int o = 32; o > 0; o >>= 1) ssum += __shfl_xor(ssum, o);
    if (t < 48) ATT[bh * 2304 + cq * 48 + t] = e / ssum;
}

// K4b: fuse attention-apply + output projection into one per-batch 192x192 matrix,
// stored TRANSPOSED (MT[b][j][D] = sum_cq attn[b,h(D),cq,D%48] * Wout[h(D)*48+cq, j])
// so the final GEMM's B-operand reads contiguous K.
__global__ void k4b_buildM(const float* __restrict__ ATT, const float* __restrict__ wout,
                           ushort_t* __restrict__ MT)
{
    int idx = blockIdx.x * 256 + threadIdx.x;      // 2*192*192 = 73728 exactly
    int b = idx / 36864; int rem = idx - b * 36864;
    int j = rem / 192;   int d = rem - j * 192;
    int h = d / 48, dd = d - h * 48;
    const float* ap = ATT + (size_t)(b * 4 + h) * 2304 + dd;   // stride 48 over cq
    const float* wp = wout + (size_t)(h * 48) * 192 + j;       // stride 192 over cq
    float s = 0.f;
#pragma unroll 8
    for (int cq = 0; cq < 48; cq++) s += ap[cq * 48] * wp[cq * 192];
    MT[idx] = f2b(s);
}

extern "C" void kernel_launch(void* const* d_in, const int* in_sizes, int n_in,
                              void* d_out, int out_size, void* d_ws, size_t ws_size,
                              hipStream_t stream) {
    const float* x     = (const float*)d_in[0];
    const float* w_qkv = (const float*)d_in[1];
    const float* b_qkv = (const float*)d_in[2];
    const float* w_dw  = (const float*)d_in[3];
    const float* b_dw  = (const float*)d_in[4];
    const float* temp  = (const float*)d_in[5];
    const float* w_out = (const float*)d_in[6];
    const float* b_out = (const float*)d_in[7];
    float* out = (float*)d_out;

    char* ws = (char*)d_ws;
    ushort_t* qkv0 = (ushort_t*)(ws + OFF_QKV0);
    ushort_t* qkv1 = (ushort_t*)(ws + OFF_QKV1);
    ushort_t* btq  = (ushort_t*)(ws + OFF_BT);
    ushort_t* wbdw = (ushort_t*)(ws + OFF_WB);
    float*    Sb   = (float*)(ws + OFF_S);
    float*    NQ   = (float*)(ws + OFF_NQ);
    float*    NK   = (float*)(ws + OFF_NK);
    float*    ATT  = (float*)(ws + OFF_ATTN);
    ushort_t* MT   = (ushort_t*)(ws + OFF_MT);

    // zero the atomic accumulators (S + NQ + NK are contiguous: 76,800 B)
    (void)hipMemsetAsync(ws + OFF_S, 0, 76800, stream);

    k0_transpose<<<432, 256, 0, stream>>>(w_qkv, btq);
    k0_cvt_w<<<21, 256, 0, stream>>>(w_dw, wbdw);
    // qkv0 = x @ w_qkv + b_qkv   (fp32 A converted in-kernel, bf16 out)
    gemm_k192<float, ushort_t><<<dim3(2048, 9), 256, 0, stream>>>(x, 192, 0, btq, 0, b_qkv, qkv0, 576);
    // qkv1 = depthwise3x3(qkv0) + b_dw   (4 px/thread, bf16 weights)
    k2_dwconv<<<9216, 256, 0, stream>>>(qkv0, wbdw, b_dw, qkv1);
    // Gram matrices + squared norms
    k3_gram<<<dim3(128, 8), 256, 0, stream>>>(qkv1, Sb, NQ, NK);
    // softmax(normalized, temperature-scaled)
    k4a_softmax<<<dim3(48, 8), 64, 0, stream>>>(Sb, NQ, NK, temp, ATT);
    // fused (blockdiag attn)^T @ Wout, transposed for the GEMM
    k4b_buildM<<<288, 256, 0, stream>>>(ATT, w_out, MT);
    // out = v @ M_b + b_out   (fp32 out)
    gemm_k192<ushort_t, float><<<dim3(2048, 3), 256, 0, stream>>>(qkv1, 576, 384, MT, 36864, b_out, out, 192);
}